// Round 5
// baseline (328.976 us; speedup 1.0000x reference)
//
#include <hip/hip_runtime.h>
#include <hip/hip_bf16.h>
#include <math.h>

#define NTOK 4096
#define DIN  1024
#define H1D  2048
#define H2D  1024
#define NE   8
#define KSEL 2

constexpr int BM = 128, BN = 128, BK = 32;
constexpr int MAX_TILES = NTOK / BM;  // 32

typedef __attribute__((ext_vector_type(8))) __bf16 bf16x8;
typedef __attribute__((ext_vector_type(4))) float  f32x4;

__device__ __forceinline__ ushort f2bf(float f) {
    union { float f; unsigned u; } c; c.f = f;
    unsigned u = c.u;
    return (ushort)((u + 0x7fffu + ((u >> 16) & 1u)) >> 16);   // RNE
}

// ---------------------------------------------------------------------------
__global__ void zero_counts(int* counts) {
    if (threadIdx.x < NE) counts[threadIdx.x] = 0;
}

__global__ void convert_x(const float* __restrict__ x, ushort* __restrict__ xbf) {
    int i = (blockIdx.x * blockDim.x + threadIdx.x) * 4;
    float4 v = *(const float4*)(x + i);
    ushort4 o;
    o.x = f2bf(v.x); o.y = f2bf(v.y); o.z = f2bf(v.z); o.w = f2bf(v.w);
    *(ushort4*)(xbf + i) = o;
}

// ---------------------------------------------------------------------------
// W[e][K][N] fp32 -> Wt[e][N][K] bf16.  Tile 64(k) x 128(n), 256 threads.
// Reads: float4 coalesced (512B per 32-lane group per k-row).
// Writes: 4 x uint4 per lane (64B contiguous per lane; lane pairs fill 128B).
// LDS [64][132] pad: store k-major, read out n-major hits all 32 banks.
// ---------------------------------------------------------------------------
__global__ __launch_bounds__(256)
void transpose_cvt(const float* __restrict__ W, ushort* __restrict__ Wt,
                   int K, int N) {
    __shared__ float t[64][132];
    const int e  = blockIdx.z;
    const int n0 = blockIdx.x * 128;
    const int k0 = blockIdx.y * 64;
    const int tid = threadIdx.x;

    const float* src = W + ((size_t)e * K + k0) * N + n0;
#pragma unroll
    for (int p = 0; p < 8; ++p) {
        int c  = tid + p * 256;          // float4 chunk id, 0..2047
        int kk = c >> 5;                 // 32 chunks per k-row
        int nn = (c & 31) * 4;
        float4 v = *(const float4*)(src + (size_t)kk * N + nn);
        t[kk][nn + 0] = v.x; t[kk][nn + 1] = v.y;
        t[kk][nn + 2] = v.z; t[kk][nn + 3] = v.w;
    }
    __syncthreads();

    const int n = tid >> 1;              // 0..127
    const int h = tid & 1;               // k-half (32 each)
    ushort outv[32];
#pragma unroll
    for (int j = 0; j < 32; ++j) outv[j] = f2bf(t[h * 32 + j][n]);
    ushort* dst = Wt + ((size_t)e * N + n0 + n) * K + k0 + h * 32;
#pragma unroll
    for (int q = 0; q < 4; ++q)
        *(uint4*)(dst + q * 8) = *(const uint4*)(outv + q * 8);
}

// ---------------------------------------------------------------------------
__global__ void topk_gate(const float* __restrict__ gates,
                          float* __restrict__ g_out,
                          int* __restrict__ counts,
                          int* __restrict__ bucket,
                          int* __restrict__ tke,
                          float* __restrict__ tkg,
                          float* __restrict__ ppart)
{
    int n = blockIdx.x * blockDim.x + threadIdx.x;
    if (n >= NTOK) return;

    // zero the fused-layer3 partial accumulators for this token's two slots
    ppart[n * 2 + 0] = 0.f;
    ppart[n * 2 + 1] = 0.f;

    float v[NE];
#pragma unroll
    for (int e = 0; e < NE; ++e) v[e] = gates[n * NE + e];

    int i1 = 0; float v1 = v[0];
#pragma unroll
    for (int e = 1; e < NE; ++e) if (v[e] > v1) { v1 = v[e]; i1 = e; }
    int i2 = -1; float v2 = -1e30f;
#pragma unroll
    for (int e = 0; e < NE; ++e) if (e != i1 && v[e] > v2) { v2 = v[e]; i2 = e; }

    float s = v1 + v2 + 1e-10f;
    float g1 = v1 / s, g2 = v2 / s;

#pragma unroll
    for (int e = 0; e < NE; ++e) {
        float gv = 0.f;
        if (e == i1) gv = g1;
        if (e == i2) gv = g2;
        g_out[n * NE + e] = gv;
    }
    tke[n * 2 + 0] = i1; tkg[n * 2 + 0] = g1;
    tke[n * 2 + 1] = i2; tkg[n * 2 + 1] = g2;

    int s1 = atomicAdd(&counts[i1], 1);
    bucket[i1 * NTOK + s1] = n * 2 + 0;
    int s2 = atomicAdd(&counts[i2], 1);
    bucket[i2 * NTOK + s2] = n * 2 + 1;
}

// ---------------------------------------------------------------------------
// Grouped bf16 MFMA GEMM. 128x128x32 tile, 4 waves (2x2 of 64x64), dbuf LDS.
// A and B staged via global_load_lds (16B/lane, linear LDS dest, XOR swizzle
// slot^=((line>>1)&3) applied by pre-permuting the SOURCE address).
// Grid 1D: e = b&7 (expert pinned to XCD), tile/col from b>>3.
// MODE 1: C = bf16(relu(acc+bias)).  MODE 2: fused relu+dot(W3) -> atomicAdd.
// ---------------------------------------------------------------------------
template<int SHIFT, int MODE>
__global__ __launch_bounds__(256)
void moe_gemm(const ushort* __restrict__ Abf, int lda,
              const ushort* __restrict__ Wt,    // [NE][N][K] bf16
              const float* __restrict__ bias,   // [NE][N]
              int N,
              const float* __restrict__ W3,     // MODE2: [NE][H2D]
              ushort* __restrict__ Cbf,         // MODE1: [NTOK*KSEL][N]
              float* __restrict__ ppart,        // MODE2: [NTOK*KSEL]
              const int* __restrict__ bucket,
              const int* __restrict__ counts,
              int K)
{
    const int b    = blockIdx.x;
    const int e    = b & 7;
    const int idx  = b >> 3;
    const int tile = idx & (MAX_TILES - 1);
    const int col0 = (idx / MAX_TILES) * BN;

    const int cnt  = counts[e];
    const int row0 = tile * BM;
    if (row0 >= cnt) return;

    __shared__ int rowmap[BM];
    __shared__ __align__(16) ushort smA[2][BM * BK];
    __shared__ __align__(16) ushort smB[2][BN * BK];

    const int tid = threadIdx.x;
    if (tid < BM) {
        int r = row0 + tid;
        rowmap[tid] = (r < cnt) ? bucket[e * NTOK + r] : -1;
    }
    __syncthreads();

    const int lane = tid & 63;
    const int wid  = tid >> 6;
    const int wm   = wid >> 1;
    const int wn   = wid & 1;

    const ushort* aSrc[2];
    const ushort* bSrc[2];
    int dstOff[2];
#pragma unroll
    for (int i = 0; i < 2; ++i) {
        int c    = (wid * 2 + i) * 64 + lane;
        int line = c >> 2;
        int slot = c & 3;
        int sch  = slot ^ ((line >> 1) & 3);
        dstOff[i] = c * 8;
        int entry = rowmap[line];
        int arow  = (entry >= 0) ? (entry >> SHIFT) : 0;
        aSrc[i] = Abf + (size_t)arow * lda + sch * 8;
        bSrc[i] = Wt + ((size_t)e * N + col0 + line) * K + sch * 8;
    }

    f32x4 acc[4][4];
#pragma unroll
    for (int i = 0; i < 4; ++i)
#pragma unroll
        for (int j = 0; j < 4; ++j)
            acc[i][j] = (f32x4){0.f, 0.f, 0.f, 0.f};

    auto stage = [&](int buf, int k0) {
#pragma unroll
        for (int i = 0; i < 2; ++i)
            __builtin_amdgcn_global_load_lds(
                (const __attribute__((address_space(1))) unsigned*)(aSrc[i] + k0),
                (__attribute__((address_space(3))) unsigned*)&smA[buf][dstOff[i]],
                16, 0, 0);
#pragma unroll
        for (int i = 0; i < 2; ++i)
            __builtin_amdgcn_global_load_lds(
                (const __attribute__((address_space(1))) unsigned*)(bSrc[i] + k0),
                (__attribute__((address_space(3))) unsigned*)&smB[buf][dstOff[i]],
                16, 0, 0);
    };

    auto compute = [&](int buf) {
        bf16x8 a[4], bfr[4];
#pragma unroll
        for (int mi = 0; mi < 4; ++mi) {
            int row  = wm * 64 + mi * 16 + (lane & 15);
            int slot = (lane >> 4) ^ ((row >> 1) & 3);
            a[mi] = *(const bf16x8*)&smA[buf][row * 32 + slot * 8];
        }
#pragma unroll
        for (int ni = 0; ni < 4; ++ni) {
            int col  = wn * 64 + ni * 16 + (lane & 15);
            int slot = (lane >> 4) ^ ((col >> 1) & 3);
            bfr[ni] = *(const bf16x8*)&smB[buf][col * 32 + slot * 8];
        }
#pragma unroll
        for (int mi = 0; mi < 4; ++mi)
#pragma unroll
            for (int ni = 0; ni < 4; ++ni)
                acc[mi][ni] = __builtin_amdgcn_mfma_f32_16x16x32_bf16(
                    a[mi], bfr[ni], acc[mi][ni], 0, 0, 0);
    };

    const int nt = K / BK;
    stage(0, 0);
    __syncthreads();
    for (int t = 0; t < nt; ++t) {
        int cur = t & 1;
        if (t + 1 < nt) stage(cur ^ 1, (t + 1) * BK);
        compute(cur);
        __syncthreads();
    }

    // ---- epilogue. C/D layout: col=lane&15, row=(lane>>4)*4+reg
    if (MODE == 1) {
        float bb[4];
#pragma unroll
        for (int ni = 0; ni < 4; ++ni)
            bb[ni] = bias[e * N + col0 + wn * 64 + ni * 16 + (lane & 15)];
#pragma unroll
        for (int mi = 0; mi < 4; ++mi) {
#pragma unroll
            for (int r = 0; r < 4; ++r) {
                int rt = wm * 64 + mi * 16 + (lane >> 4) * 4 + r;
                int entry = rowmap[rt];
                if (entry < 0) continue;
                ushort* crow = Cbf + (size_t)entry * N + col0;
#pragma unroll
                for (int ni = 0; ni < 4; ++ni) {
                    float val = fmaxf(acc[mi][ni][r] + bb[ni], 0.f);
                    crow[wn * 64 + ni * 16 + (lane & 15)] = f2bf(val);
                }
            }
        }
    } else {
        float bb[4], w3l[4];
#pragma unroll
        for (int ni = 0; ni < 4; ++ni) {
            int cg = col0 + wn * 64 + ni * 16 + (lane & 15);
            bb[ni]  = bias[e * N + cg];
            w3l[ni] = W3[e * H2D + cg];
        }
#pragma unroll
        for (int mi = 0; mi < 4; ++mi) {
#pragma unroll
            for (int r = 0; r < 4; ++r) {
                float s = 0.f;
#pragma unroll
                for (int ni = 0; ni < 4; ++ni)
                    s += fmaxf(acc[mi][ni][r] + bb[ni], 0.f) * w3l[ni];
#pragma unroll
                for (int off = 1; off < 16; off <<= 1)
                    s += __shfl_xor(s, off, 16);
                if ((lane & 15) == 0) {
                    int rt = wm * 64 + mi * 16 + (lane >> 4) * 4 + r;
                    int entry = rowmap[rt];
                    if (entry >= 0) atomicAdd(&ppart[entry], s);
                }
            }
        }
    }
}

// ---------------------------------------------------------------------------
__global__ void finalize(const float* __restrict__ pp, const float* __restrict__ b3,
                         const int* __restrict__ tke, const float* __restrict__ tkg,
                         float* __restrict__ pred) {
    int n = blockIdx.x * blockDim.x + threadIdx.x;
    if (n >= NTOK) return;
    float r = 0.f;
#pragma unroll
    for (int k = 0; k < KSEL; ++k) {
        int p = n * 2 + k;
        int ee = tke[p];
        float y = 1.f / (1.f + expf(-(pp[p] + b3[ee])));
        r += tkg[p] * y;
    }
    pred[n] = r;
}

// ---------------------------------------------------------------------------
extern "C" void kernel_launch(void* const* d_in, const int* in_sizes, int n_in,
                              void* d_out, int out_size, void* d_ws, size_t ws_size,
                              hipStream_t stream)
{
    const float* x     = (const float*)d_in[0];
    const float* gates = (const float*)d_in[1];
    const float* W1    = (const float*)d_in[2];
    const float* b1    = (const float*)d_in[3];
    const float* W2    = (const float*)d_in[4];
    const float* b2    = (const float*)d_in[5];
    const float* W3    = (const float*)d_in[6];
    const float* b3    = (const float*)d_in[7];

    float* out  = (float*)d_out;
    float* pred = out;
    float* gout = out + NTOK;

    // ws (~73 MB): hdr 1MB | xbf 8MB | h1bf 32MB | Wtbuf 32MB (shared W1t/W2t)
    char* ws = (char*)d_ws;
    int*    counts = (int*)(ws);
    int*    bucket = (int*)(ws + 4096);
    int*    tke    = (int*)(ws + 4096 + 131072);
    float*  tkg    = (float*)(ws + 4096 + 131072 + 32768);
    float*  ppart  = (float*)(ws + 4096 + 131072 + 65536);
    ushort* xbf    = (ushort*)(ws + (1 << 20));
    ushort* h1bf   = (ushort*)(ws + (1 << 20) + (size_t)NTOK * DIN * 2);
    ushort* wtbuf  = (ushort*)(ws + (1 << 20) + (size_t)NTOK * DIN * 2
                                  + (size_t)NTOK * KSEL * H1D * 2);

    zero_counts<<<1, 64, 0, stream>>>(counts);
    topk_gate<<<NTOK / 256, 256, 0, stream>>>(gates, gout, counts, bucket,
                                              tke, tkg, ppart);
    convert_x<<<NTOK * DIN / 4 / 256, 256, 0, stream>>>(x, xbf);

    // W1 [e][1024][2048] -> Wt [e][2048][1024]
    transpose_cvt<<<dim3(H1D / 128, DIN / 64, NE), 256, 0, stream>>>(
        W1, wtbuf, DIN, H1D);
    moe_gemm<1, 1><<<NE * (H1D / BN) * MAX_TILES, 256, 0, stream>>>(
        xbf, DIN, wtbuf, b1, H1D, nullptr, h1bf, nullptr, bucket, counts, DIN);

    // W2 [e][2048][1024] -> Wt [e][1024][2048]
    transpose_cvt<<<dim3(H2D / 128, H1D / 64, NE), 256, 0, stream>>>(
        W2, wtbuf, H1D, H2D);
    moe_gemm<0, 2><<<NE * (H2D / BN) * MAX_TILES, 256, 0, stream>>>(
        h1bf, H1D, wtbuf, b2, H2D, W3, nullptr, ppart, bucket, counts, H1D);

    finalize<<<NTOK / 256, 256, 0, stream>>>(ppart, b3, tke, tkg, pred);
}